// Round 7
// baseline (720.800 us; speedup 1.0000x reference)
//
#include <hip/hip_runtime.h>
#include <math.h>

#define N_NODES 50000
#define E_EDGES 250000
#define E_TOT   750000
#define HID 64
#define L_LAYERS 2
#define IN_DIM_ 256
#define ATT_SCALE 0.125f
#define LOG2E 1.44269504f
#define EPS_BN 1e-5f
#define NCHUNK 49       // ceil(50000/1024)
#define GX 782          // ceil(50000/64)

#define PACK_REL (6 * 512 * 64)
#define PACK_FC  (2 * 64 * 64)
#define PACK_DIM (256 * 64)
#define HIST_B   2930   // ceil(750000/256)
#define PACK_B   864    // (PACK_REL+PACK_FC+PACK_DIM)/256
#define CVT_B    3125   // 3.2M/4/256

typedef __attribute__((ext_vector_type(8))) short bf16x8;
typedef __attribute__((ext_vector_type(4))) float f32x4;

static __device__ __forceinline__ unsigned short f2bf(float f) {
    unsigned u = __float_as_uint(f);
    unsigned r = (u + 0x7fff + ((u >> 16) & 1)) >> 16;
    return (unsigned short)r;
}
static __device__ __forceinline__ float bf2f(unsigned u) {
    return __uint_as_float(u << 16);
}

// sum across each 16-lane row via DPP butterfly (4 VALU adds, no LDS)
static __device__ __forceinline__ float rowsum16(float x) {
    int t;
    t = __builtin_amdgcn_update_dpp(0, __float_as_int(x), 0xB1, 0xf, 0xf, true);  // quad_perm(1,0,3,2)
    x += __int_as_float(t);
    t = __builtin_amdgcn_update_dpp(0, __float_as_int(x), 0x4E, 0xf, 0xf, true);  // quad_perm(2,3,0,1)
    x += __int_as_float(t);
    t = __builtin_amdgcn_update_dpp(0, __float_as_int(x), 0x141, 0xf, 0xf, true); // row_half_mirror
    x += __int_as_float(t);
    t = __builtin_amdgcn_update_dpp(0, __float_as_int(x), 0x140, 0xf, 0xf, true); // row_mirror
    x += __int_as_float(t);
    return x;
}

// ----------------------- U1: hist ∪ pack ∪ cvt -------------------------------
// Merged-relation histogram: count[dst] over all 750K edges.

__global__ __launch_bounds__(256) void u1_kernel(
        const int* __restrict__ d0, const int* __restrict__ d1, const int* __restrict__ d2,
        int* __restrict__ count,
        const float* __restrict__ Wsrc, const float* __restrict__ Wdst,
        const float* __restrict__ Wfc, const float* __restrict__ Wdim,
        unsigned short* __restrict__ WtRel, unsigned short* __restrict__ WtFc,
        unsigned short* __restrict__ WtDim,
        const float* __restrict__ x, unsigned short* __restrict__ xb) {
    int b = blockIdx.x;
    if (b < HIST_B) {
        int i = b * 256 + threadIdx.x;
        if (i < E_TOT) {
            int r = i / E_EDGES;
            int e = i - r * E_EDGES;
            const int* dst = (r == 0) ? d0 : ((r == 1) ? d1 : d2);
            atomicAdd(&count[dst[e]], 1);
        }
    } else if (b < HIST_B + PACK_B) {
        int i = (b - HIST_B) * 256 + threadIdx.x;
        if (i < PACK_REL) {
            int k = i & 63;
            int n = (i >> 6) & 511;
            int lr = i >> 15;
            const float* srcm = (n < 256) ? Wsrc : Wdst;
            WtRel[i] = f2bf(srcm[((size_t)lr * 64 + k) * 256 + (n & 255)]);
        } else if (i < PACK_REL + PACK_FC) {
            int j = i - PACK_REL;
            int l = j >> 12, rem = j & 4095;
            int k = rem & 63, n = rem >> 6;
            WtFc[j] = f2bf(Wfc[(size_t)l * 4096 + k * 64 + n]);
        } else if (i < PACK_REL + PACK_FC + PACK_DIM) {
            int j = i - PACK_REL - PACK_FC;
            int k = j & 63, n = j >> 6;
            WtDim[j] = f2bf(Wdim[(size_t)k * 256 + n]);
        }
    } else {
        int i = ((b - HIST_B - PACK_B) * 256 + threadIdx.x) * 4;
        if (i < N_NODES * HID) {
            float4 v = *(const float4*)(x + i);
            uint2 o;
            o.x = (unsigned)f2bf(v.x) | ((unsigned)f2bf(v.y) << 16);
            o.y = (unsigned)f2bf(v.z) | ((unsigned)f2bf(v.w) << 16);
            *(uint2*)(xb + i) = o;
        }
    }
}

// ----------------------------- scan (3-phase, single segment) ----------------

__global__ __launch_bounds__(256) void scan_partial(const int* __restrict__ count,
                                                    int* __restrict__ bsum) {
    int b = blockIdx.x;                 // 0..48
    int tid = threadIdx.x;
    int i0 = b * 1024 + tid * 4;
    int s = 0;
    if (i0 + 3 < N_NODES) {
        int4 v = *(const int4*)(count + i0);
        s = v.x + v.y + v.z + v.w;
    } else {
        for (int j = 0; j < 4; ++j)
            if (i0 + j < N_NODES) s += count[i0 + j];
    }
    for (int o = 1; o < 64; o <<= 1) s += __shfl_xor(s, o, 64);
    __shared__ int wsum[4];
    if ((tid & 63) == 0) wsum[tid >> 6] = s;
    __syncthreads();
    if (tid == 0) bsum[b] = wsum[0] + wsum[1] + wsum[2] + wsum[3];
}

__global__ __launch_bounds__(64) void scan_mid(const int* __restrict__ bsum,
                                               int* __restrict__ bpre) {
    int tid = threadIdx.x;   // 0..63
    int v = (tid < NCHUNK) ? bsum[tid] : 0;
    int x = v;
    for (int o = 1; o < 64; o <<= 1) {
        int y = __shfl_up(x, o, 64);
        if (tid >= o) x += y;
    }
    if (tid < NCHUNK) bpre[tid] = x - v;
}

__global__ __launch_bounds__(256) void scan_final(const int* __restrict__ count,
                                                  const int* __restrict__ bpre,
                                                  int* __restrict__ row_off,
                                                  int* __restrict__ cursor) {
    int b = blockIdx.x;
    int tid = threadIdx.x;
    int i0 = b * 1024 + tid * 4;
    int v[4] = {0, 0, 0, 0};
    if (i0 + 3 < N_NODES) {
        int4 t = *(const int4*)(count + i0);
        v[0] = t.x; v[1] = t.y; v[2] = t.z; v[3] = t.w;
    } else {
        for (int j = 0; j < 4; ++j)
            if (i0 + j < N_NODES) v[j] = count[i0 + j];
    }
    int tsum = v[0] + v[1] + v[2] + v[3];
    __shared__ int A[256], B[256];
    A[tid] = tsum;
    __syncthreads();
    int* s = A; int* d = B;
    for (int o = 1; o < 256; o <<= 1) {
        int x = s[tid];
        if (tid >= o) x += s[tid - o];
        d[tid] = x;
        __syncthreads();
        int* t = s; s = d; d = t;
    }
    int run = bpre[b] + s[tid] - tsum;
    for (int j = 0; j < 4; ++j) {
        int idx = i0 + j;
        if (idx < N_NODES) { row_off[idx] = run; cursor[idx] = run; run += v[j]; }
    }
    if (b == NCHUNK - 1 && tid == 255) row_off[N_NODES] = E_TOT;
}

// ----------------------------- scatter (merged CSR) --------------------------
// entry = rel * N_NODES + src  (linear index into projAll rows)

__global__ void scatter_kernel(const int* __restrict__ s0, const int* __restrict__ d0,
                               const int* __restrict__ s1, const int* __restrict__ d1,
                               const int* __restrict__ s2, const int* __restrict__ d2,
                               int* __restrict__ cursor, int* __restrict__ csr_idx) {
    int i = blockIdx.x * blockDim.x + threadIdx.x;
    if (i >= E_TOT) return;
    int r = i / E_EDGES;
    int e = i - r * E_EDGES;
    const int* src = (r == 0) ? s0 : ((r == 1) ? s1 : s2);
    const int* dst = (r == 0) ? d0 : ((r == 1) ? d1 : d2);
    int d = dst[e];
    int pos = atomicAdd(&cursor[d], 1);
    csr_idx[pos] = r * N_NODES + src[e];
}

// --------------------------- MFMA projection (bf16 in) -----------------------
// D'[feat][node]: A-frag from Wt[512][64], B-frag from h[M][64]. C/D:
// col=lane&15 (node), row=quad*4+reg (feature) -> lane owns 4 consecutive
// features of one node: packed 8B bf16 store. No LDS, no barriers.

__global__ __launch_bounds__(256) void gemm_proj3(const unsigned short* __restrict__ hB,
                                                  const unsigned short* __restrict__ WtL,
                                                  unsigned short* __restrict__ projAll,
                                                  int M) {
    int r = blockIdx.z;
    const unsigned short* Wt = WtL + (size_t)r * 512 * 64;
    unsigned short* out = projAll + (size_t)r * N_NODES * 512;

    int tid = threadIdx.x;
    int wave = tid >> 6, lane = tid & 63;
    int q = lane >> 4, li = lane & 15;
    int nodeBase = blockIdx.x * 64 + (wave >> 1) * 32;
    int featBase = blockIdx.y * 64 + (wave & 1) * 32;

    const unsigned short* aptr[2];
    const unsigned short* bptr[2];
    #pragma unroll
    for (int t = 0; t < 2; ++t) {
        aptr[t] = Wt + (size_t)(featBase + t * 16 + li) * 64 + q * 8;
        int node = nodeBase + t * 16 + li; if (node >= M) node = M - 1;
        bptr[t] = hB + (size_t)node * 64 + q * 8;
    }
    f32x4 acc[2][2];
    #pragma unroll
    for (int a = 0; a < 2; ++a)
        #pragma unroll
        for (int bq = 0; bq < 2; ++bq)
            #pragma unroll
            for (int i = 0; i < 4; ++i) acc[a][bq][i] = 0.f;

    #pragma unroll
    for (int s = 0; s < 2; ++s) {
        bf16x8 a[2], b[2];
        #pragma unroll
        for (int t = 0; t < 2; ++t) {
            a[t] = *(const bf16x8*)(aptr[t] + s * 32);
            b[t] = *(const bf16x8*)(bptr[t] + s * 32);
        }
        #pragma unroll
        for (int ft = 0; ft < 2; ++ft)
            #pragma unroll
            for (int nt = 0; nt < 2; ++nt)
                acc[ft][nt] = __builtin_amdgcn_mfma_f32_16x16x32_bf16(a[ft], b[nt], acc[ft][nt], 0, 0, 0);
    }
    #pragma unroll
    for (int ft = 0; ft < 2; ++ft) {
        int f0 = featBase + ft * 16 + q * 4;
        #pragma unroll
        for (int nt = 0; nt < 2; ++nt) {
            int node = nodeBase + nt * 16 + li;
            if (node >= M) continue;
            unsigned lo = (unsigned)f2bf(acc[ft][nt][0]) | ((unsigned)f2bf(acc[ft][nt][1]) << 16);
            unsigned hi = (unsigned)f2bf(acc[ft][nt][2]) | ((unsigned)f2bf(acc[ft][nt][3]) << 16);
            uint2 pk; pk.x = lo; pk.y = hi;
            *(uint2*)(out + (size_t)node * 512 + f0) = pk;
        }
    }
}

// ----------------------- BN-fused B-fragment helpers -------------------------
// y fp32 [M][64]; normalize with per-column stats -> bf16 fragment in regs.

static __device__ __forceinline__ void bn_coef(const float* __restrict__ a1,
        const float* __restrict__ a2, const float* __restrict__ gm,
        const float* __restrict__ bt, int q, float sc[2][8], float sh[2][8]) {
    const float invN = 1.0f / (float)N_NODES;
    #pragma unroll
    for (int s = 0; s < 2; ++s) {
        int k0 = q * 8 + s * 32;
        #pragma unroll
        for (int jj = 0; jj < 8; jj += 4) {
            float4 m1 = *(const float4*)(a1 + k0 + jj);
            float4 m2 = *(const float4*)(a2 + k0 + jj);
            float4 g  = *(const float4*)(gm + k0 + jj);
            float4 b  = *(const float4*)(bt + k0 + jj);
            float mm1[4] = {m1.x, m1.y, m1.z, m1.w};
            float mm2[4] = {m2.x, m2.y, m2.z, m2.w};
            float gg[4]  = {g.x, g.y, g.z, g.w};
            float bb[4]  = {b.x, b.y, b.z, b.w};
            #pragma unroll
            for (int u = 0; u < 4; ++u) {
                float mu = mm1[u] * invN;
                float var = mm2[u] * invN - mu * mu;
                float rs = rsqrtf(var + EPS_BN);
                float s_ = gg[u] * rs;
                sc[s][jj + u] = s_;
                sh[s][jj + u] = bb[u] - mu * s_;
            }
        }
    }
}

static __device__ __forceinline__ bf16x8 bn_frag(const float* __restrict__ y, int node,
        int s, const float sc[2][8], const float sh[2][8], int q) {
    int k0 = q * 8 + s * 32;
    const float* yp = y + (size_t)node * 64 + k0;
    float4 y0 = *(const float4*)(yp);
    float4 y1 = *(const float4*)(yp + 4);
    float v[8] = {y0.x, y0.y, y0.z, y0.w, y1.x, y1.y, y1.z, y1.w};
    bf16x8 f;
    #pragma unroll
    for (int j = 0; j < 8; ++j) f[j] = (short)f2bf(v[j] * sc[s][j] + sh[s][j]);
    return f;
}

// layer-1 projection with fused bn_apply on the fp32 y input
__global__ __launch_bounds__(256) void proj3_bn(const float* __restrict__ y,
        const float* __restrict__ a1, const float* __restrict__ a2,
        const float* __restrict__ gm, const float* __restrict__ bt,
        const unsigned short* __restrict__ WtL, unsigned short* __restrict__ projAll,
        int M) {
    int r = blockIdx.z;
    const unsigned short* Wt = WtL + (size_t)r * 512 * 64;
    unsigned short* out = projAll + (size_t)r * N_NODES * 512;

    int tid = threadIdx.x;
    int wave = tid >> 6, lane = tid & 63;
    int q = lane >> 4, li = lane & 15;
    int nodeBase = blockIdx.x * 64 + (wave >> 1) * 32;
    int featBase = blockIdx.y * 64 + (wave & 1) * 32;

    float sc[2][8], sh[2][8];
    bn_coef(a1, a2, gm, bt, q, sc, sh);

    const unsigned short* aptr[2];
    int nodes[2];
    #pragma unroll
    for (int t = 0; t < 2; ++t) {
        aptr[t] = Wt + (size_t)(featBase + t * 16 + li) * 64 + q * 8;
        int node = nodeBase + t * 16 + li; if (node >= M) node = M - 1;
        nodes[t] = node;
    }
    f32x4 acc[2][2];
    #pragma unroll
    for (int a = 0; a < 2; ++a)
        #pragma unroll
        for (int bq = 0; bq < 2; ++bq)
            #pragma unroll
            for (int i = 0; i < 4; ++i) acc[a][bq][i] = 0.f;

    #pragma unroll
    for (int s = 0; s < 2; ++s) {
        bf16x8 a[2], b[2];
        #pragma unroll
        for (int t = 0; t < 2; ++t) {
            a[t] = *(const bf16x8*)(aptr[t] + s * 32);
            b[t] = bn_frag(y, nodes[t], s, sc, sh, q);
        }
        #pragma unroll
        for (int ft = 0; ft < 2; ++ft)
            #pragma unroll
            for (int nt = 0; nt < 2; ++nt)
                acc[ft][nt] = __builtin_amdgcn_mfma_f32_16x16x32_bf16(a[ft], b[nt], acc[ft][nt], 0, 0, 0);
    }
    #pragma unroll
    for (int ft = 0; ft < 2; ++ft) {
        int f0 = featBase + ft * 16 + q * 4;
        #pragma unroll
        for (int nt = 0; nt < 2; ++nt) {
            int node = nodeBase + nt * 16 + li;
            if (node >= M) continue;
            unsigned lo = (unsigned)f2bf(acc[ft][nt][0]) | ((unsigned)f2bf(acc[ft][nt][1]) << 16);
            unsigned hi = (unsigned)f2bf(acc[ft][nt][2]) | ((unsigned)f2bf(acc[ft][nt][3]) << 16);
            uint2 pk; pk.x = lo; pk.y = hi;
            *(uint2*)(out + (size_t)node * 512 + f0) = pk;
        }
    }
}

// final projection (Nout=256) with fused bn_apply, fp32 out + bias
__global__ __launch_bounds__(256) void final_bn(const float* __restrict__ y,
        const float* __restrict__ a1, const float* __restrict__ a2,
        const float* __restrict__ gm, const float* __restrict__ bt,
        const unsigned short* __restrict__ Wt, const float* __restrict__ bias,
        float* __restrict__ out, int M) {
    int tid = threadIdx.x;
    int wave = tid >> 6, lane = tid & 63;
    int q = lane >> 4, li = lane & 15;
    int nodeBase = blockIdx.x * 64 + (wave >> 1) * 32;
    int featBase = blockIdx.y * 64 + (wave & 1) * 32;

    float sc[2][8], sh[2][8];
    bn_coef(a1, a2, gm, bt, q, sc, sh);

    const unsigned short* aptr[2];
    int nodes[2];
    #pragma unroll
    for (int t = 0; t < 2; ++t) {
        aptr[t] = Wt + (size_t)(featBase + t * 16 + li) * 64 + q * 8;
        int node = nodeBase + t * 16 + li; if (node >= M) node = M - 1;
        nodes[t] = node;
    }
    f32x4 acc[2][2];
    #pragma unroll
    for (int a = 0; a < 2; ++a)
        #pragma unroll
        for (int bq = 0; bq < 2; ++bq)
            #pragma unroll
            for (int i = 0; i < 4; ++i) acc[a][bq][i] = 0.f;

    #pragma unroll
    for (int s = 0; s < 2; ++s) {
        bf16x8 a[2], b[2];
        #pragma unroll
        for (int t = 0; t < 2; ++t) {
            a[t] = *(const bf16x8*)(aptr[t] + s * 32);
            b[t] = bn_frag(y, nodes[t], s, sc, sh, q);
        }
        #pragma unroll
        for (int ft = 0; ft < 2; ++ft)
            #pragma unroll
            for (int nt = 0; nt < 2; ++nt)
                acc[ft][nt] = __builtin_amdgcn_mfma_f32_16x16x32_bf16(a[ft], b[nt], acc[ft][nt], 0, 0, 0);
    }
    #pragma unroll
    for (int ft = 0; ft < 2; ++ft) {
        int f0 = featBase + ft * 16 + q * 4;
        float b0 = bias[f0], b1 = bias[f0 + 1], b2 = bias[f0 + 2], b3 = bias[f0 + 3];
        #pragma unroll
        for (int nt = 0; nt < 2; ++nt) {
            int node = nodeBase + nt * 16 + li;
            if (node >= M) continue;
            float4 o;
            o.x = acc[ft][nt][0] + b0; o.y = acc[ft][nt][1] + b1;
            o.z = acc[ft][nt][2] + b2; o.w = acc[ft][nt][3] + b3;
            *(float4*)(out + (size_t)node * IN_DIM_ + f0) = o;
        }
    }
}

// fc gemm: hm bf16 -> y = relu(hm @ Wfc + b), fp32 out
__global__ __launch_bounds__(256) void gemm_fc(const unsigned short* __restrict__ hB,
                                               const unsigned short* __restrict__ Wt,
                                               const float* __restrict__ bias,
                                               float* __restrict__ out, int M) {
    int tid = threadIdx.x;
    int wave = tid >> 6, lane = tid & 63;
    int q = lane >> 4, li = lane & 15;
    int nodeBase = blockIdx.x * 64 + (wave >> 1) * 32;
    int featBase = (wave & 1) * 32;

    const unsigned short* aptr[2];
    const unsigned short* bptr[2];
    #pragma unroll
    for (int t = 0; t < 2; ++t) {
        aptr[t] = Wt + (size_t)(featBase + t * 16 + li) * 64 + q * 8;
        int node = nodeBase + t * 16 + li; if (node >= M) node = M - 1;
        bptr[t] = hB + (size_t)node * 64 + q * 8;
    }
    f32x4 acc[2][2];
    #pragma unroll
    for (int a = 0; a < 2; ++a)
        #pragma unroll
        for (int bq = 0; bq < 2; ++bq)
            #pragma unroll
            for (int i = 0; i < 4; ++i) acc[a][bq][i] = 0.f;

    #pragma unroll
    for (int s = 0; s < 2; ++s) {
        bf16x8 a[2], b[2];
        #pragma unroll
        for (int t = 0; t < 2; ++t) {
            a[t] = *(const bf16x8*)(aptr[t] + s * 32);
            b[t] = *(const bf16x8*)(bptr[t] + s * 32);
        }
        #pragma unroll
        for (int ft = 0; ft < 2; ++ft)
            #pragma unroll
            for (int nt = 0; nt < 2; ++nt)
                acc[ft][nt] = __builtin_amdgcn_mfma_f32_16x16x32_bf16(a[ft], b[nt], acc[ft][nt], 0, 0, 0);
    }
    #pragma unroll
    for (int ft = 0; ft < 2; ++ft) {
        int f0 = featBase + ft * 16 + q * 4;
        float b0 = bias[f0], b1 = bias[f0 + 1], b2 = bias[f0 + 2], b3 = bias[f0 + 3];
        #pragma unroll
        for (int nt = 0; nt < 2; ++nt) {
            int node = nodeBase + nt * 16 + li;
            if (node >= M) continue;
            float4 o;
            o.x = fmaxf(acc[ft][nt][0] + b0, 0.f);
            o.y = fmaxf(acc[ft][nt][1] + b1, 0.f);
            o.z = fmaxf(acc[ft][nt][2] + b2, 0.f);
            o.w = fmaxf(acc[ft][nt][3] + b3, 0.f);
            *(float4*)(out + (size_t)node * 64 + f0) = o;
        }
    }
}

// ----------------- fused attention: merged CSR, 3 rel + head-mean ------------
// One wave per dst node, ONE loop over all-relation edges (avg deg ~15 -> deep
// gather MLP). csr_idx entry = rel*N + src row index into projAll.
// Per-row rel is wave-uniform -> uniform branch selects fd regs / accumulators.

__global__ __launch_bounds__(256) void agg_fused(const int* __restrict__ ro,
                                                 const int* __restrict__ csr_idx,
                                                 const unsigned short* __restrict__ projAll,
                                                 unsigned short* __restrict__ hm) {
    int wave = (blockIdx.x * 256 + threadIdx.x) >> 6;
    int lane = threadIdx.x & 63;
    if (wave >= N_NODES) return;
    int dst = wave;
    int base = ro[dst];
    int degT = ro[dst + 1] - base;

    const float FS = ATT_SCALE * LOG2E;
    float fA0, fA1, fA2, fA3, fB0, fB1, fB2, fB3, fC0, fC1, fC2, fC3;
    {
        uint2 v0 = *(const uint2*)(projAll + (size_t)dst * 512 + 256 + lane * 4);
        uint2 v1 = *(const uint2*)(projAll + ((size_t)N_NODES + dst) * 512 + 256 + lane * 4);
        uint2 v2 = *(const uint2*)(projAll + ((size_t)2 * N_NODES + dst) * 512 + 256 + lane * 4);
        fA0 = bf2f(v0.x & 0xffff) * FS; fA1 = __uint_as_float(v0.x & 0xffff0000u) * FS;
        fA2 = bf2f(v0.y & 0xffff) * FS; fA3 = __uint_as_float(v0.y & 0xffff0000u) * FS;
        fB0 = bf2f(v1.x & 0xffff) * FS; fB1 = __uint_as_float(v1.x & 0xffff0000u) * FS;
        fB2 = bf2f(v1.y & 0xffff) * FS; fB3 = __uint_as_float(v1.y & 0xffff0000u) * FS;
        fC0 = bf2f(v2.x & 0xffff) * FS; fC1 = __uint_as_float(v2.x & 0xffff0000u) * FS;
        fC2 = bf2f(v2.y & 0xffff) * FS; fC3 = __uint_as_float(v2.y & 0xffff0000u) * FS;
    }
    float dA = 0.f, dB = 0.f, dC = 0.f;
    float aA0 = 0.f, aA1 = 0.f, aA2 = 0.f, aA3 = 0.f;
    float aB0 = 0.f, aB1 = 0.f, aB2 = 0.f, aB3 = 0.f;
    float aC0 = 0.f, aC1 = 0.f, aC2 = 0.f, aC3 = 0.f;

    const int* cs = csr_idx + base;
    for (int c0 = 0; c0 < degT; c0 += 64) {
        int nc = degT - c0; if (nc > 64) nc = 64;
        int idxv = (lane < nc) ? cs[c0 + lane] : 0;
        for (int j0 = 0; j0 < nc; j0 += 16) {
            int ntb = nc - j0; if (ntb > 16) ntb = 16;
            uint2 rowv[16];
            #pragma unroll
            for (int t = 0; t < 16; ++t) {
                if (t < ntb) {   // wave-uniform
                    int idx = __shfl(idxv, j0 + t, 64);
                    rowv[t] = *(const uint2*)(projAll + (size_t)idx * 512 + lane * 4);
                }
            }
            #pragma unroll
            for (int t = 0; t < 16; ++t) {
                if (t < ntb) {   // wave-uniform
                    int idx = __shfl(idxv, j0 + t, 64);
                    float s0 = __uint_as_float(rowv[t].x << 16);
                    float s1 = __uint_as_float(rowv[t].x & 0xffff0000u);
                    float s2 = __uint_as_float(rowv[t].y << 16);
                    float s3 = __uint_as_float(rowv[t].y & 0xffff0000u);
                    if (idx < N_NODES) {
                        float p = s0 * fA0 + s1 * fA1 + s2 * fA2 + s3 * fA3;
                        p = rowsum16(p);
                        p = fminf(fmaxf(p, -60.f), 60.f);
                        float pe = __builtin_amdgcn_exp2f(p);
                        dA += pe;
                        aA0 += pe * s0; aA1 += pe * s1; aA2 += pe * s2; aA3 += pe * s3;
                    } else if (idx < 2 * N_NODES) {
                        float p = s0 * fB0 + s1 * fB1 + s2 * fB2 + s3 * fB3;
                        p = rowsum16(p);
                        p = fminf(fmaxf(p, -60.f), 60.f);
                        float pe = __builtin_amdgcn_exp2f(p);
                        dB += pe;
                        aB0 += pe * s0; aB1 += pe * s1; aB2 += pe * s2; aB3 += pe * s3;
                    } else {
                        float p = s0 * fC0 + s1 * fC1 + s2 * fC2 + s3 * fC3;
                        p = rowsum16(p);
                        p = fminf(fmaxf(p, -60.f), 60.f);
                        float pe = __builtin_amdgcn_exp2f(p);
                        dC += pe;
                        aC0 += pe * s0; aC1 += pe * s1; aC2 += pe * s2; aC3 += pe * s3;
                    }
                }
            }
        }
    }
    float iA = 1.0f / fmaxf(dA, 1e-9f);
    float iB = 1.0f / fmaxf(dB, 1e-9f);
    float iC = 1.0f / fmaxf(dC, 1e-9f);
    float t0 = aA0 * iA + aB0 * iB + aC0 * iC;
    float t1 = aA1 * iA + aB1 * iB + aC1 * iC;
    float t2 = aA2 * iA + aB2 * iB + aC2 * iC;
    float t3 = aA3 * iA + aB3 * iB + aC3 * iC;

    // mean over heads: feature f of head h lives at lane h*16 + f/4, slot f&3
    t0 += __shfl_xor(t0, 16, 64); t0 += __shfl_xor(t0, 32, 64);
    t1 += __shfl_xor(t1, 16, 64); t1 += __shfl_xor(t1, 32, 64);
    t2 += __shfl_xor(t2, 16, 64); t2 += __shfl_xor(t2, 32, 64);
    t3 += __shfl_xor(t3, 16, 64); t3 += __shfl_xor(t3, 32, 64);
    if (lane < 16) {
        unsigned lo = (unsigned)f2bf(t0 * 0.25f) | ((unsigned)f2bf(t1 * 0.25f) << 16);
        unsigned hi = (unsigned)f2bf(t2 * 0.25f) | ((unsigned)f2bf(t3 * 0.25f) << 16);
        uint2 pk; pk.x = lo; pk.y = hi;
        *(uint2*)(hm + (size_t)dst * 64 + lane * 4) = pk;
    }
}

// ----------------------------- batchnorm stats -------------------------------

__global__ __launch_bounds__(256) void bn_reduce_kernel(const float* __restrict__ y,
                                                        float* __restrict__ acc1,
                                                        float* __restrict__ acc2) {
    int tid = threadIdx.x;
    int c = tid & 63;
    int g = tid >> 6;
    int rowStart = blockIdx.x * 4 + g;
    int stride = gridDim.x * 4;
    float s1 = 0.f, s2 = 0.f;
    for (int r = rowStart; r < N_NODES; r += stride) {
        float v = y[(size_t)r * 64 + c];
        s1 += v; s2 += v * v;
    }
    __shared__ float l1[4][64], l2[4][64];
    l1[g][c] = s1; l2[g][c] = s2;
    __syncthreads();
    if (g == 0) {
        s1 = l1[0][c] + l1[1][c] + l1[2][c] + l1[3][c];
        s2 = l2[0][c] + l2[1][c] + l2[2][c] + l2[3][c];
        atomicAdd(&acc1[c], s1);
        atomicAdd(&acc2[c], s2);
    }
}

// ----------------------------- launch ----------------------------------------

extern "C" void kernel_launch(void* const* d_in, const int* in_sizes, int n_in,
                              void* d_out, int out_size, void* d_ws, size_t ws_size,
                              hipStream_t stream) {
    const float* x     = (const float*)d_in[0];
    const int* srcs[3] = {(const int*)d_in[1], (const int*)d_in[3], (const int*)d_in[5]};
    const int* dsts[3] = {(const int*)d_in[2], (const int*)d_in[4], (const int*)d_in[6]};
    const float* Wsrc  = (const float*)d_in[7];
    const float* Wdst  = (const float*)d_in[8];
    const float* Wfc   = (const float*)d_in[9];
    const float* bfc   = (const float*)d_in[10];
    const float* gamma = (const float*)d_in[11];
    const float* beta  = (const float*)d_in[12];
    const float* Wdim  = (const float*)d_in[13];
    const float* bdim  = (const float*)d_in[14];
    float* out = (float*)d_out;

    char* ws = (char*)d_ws;
    size_t off = 0;
    auto alloc = [&](size_t bytes) -> void* {
        void* p = ws + off;
        off += (bytes + 255) & ~(size_t)255;
        return p;
    };
    // bnacc + count contiguous so one memset zeros both
    float* bnacc  = (float*)alloc(256 * 4);                    // [0..127] l0, [128..255] l1
    int* count    = (int*)alloc((size_t)N_NODES * 4);
    int* cursor   = (int*)alloc((size_t)N_NODES * 4);
    int* row_off  = (int*)alloc((size_t)(N_NODES + 1) * 4);
    int* csr_idx  = (int*)alloc((size_t)E_TOT * 4);
    int* bsum     = (int*)alloc(256 * 4);
    int* bpre     = (int*)alloc(256 * 4);
    unsigned short* projAll = (unsigned short*)alloc((size_t)3 * N_NODES * 512 * 2);
    unsigned short* hm      = (unsigned short*)alloc((size_t)N_NODES * HID * 2);
    float* ybuf             = (float*)alloc((size_t)N_NODES * HID * 4);
    unsigned short* xb      = (unsigned short*)alloc((size_t)N_NODES * HID * 2);
    unsigned short* WtRel   = (unsigned short*)alloc((size_t)PACK_REL * 2);
    unsigned short* WtFc    = (unsigned short*)alloc((size_t)PACK_FC * 2);
    unsigned short* WtDim   = (unsigned short*)alloc((size_t)PACK_DIM * 2);

    // zero bnacc (1 KB) + count (200 KB), contiguous
    hipMemsetAsync(bnacc, 0, 1024 + (size_t)N_NODES * 4, stream);

    // U1: hist ∪ weight-pack ∪ x->bf16 cast
    u1_kernel<<<HIST_B + PACK_B + CVT_B, 256, 0, stream>>>(
        dsts[0], dsts[1], dsts[2], count, Wsrc, Wdst, Wfc, Wdim,
        WtRel, WtFc, WtDim, x, xb);

    scan_partial<<<NCHUNK, 256, 0, stream>>>(count, bsum);
    scan_mid<<<1, 64, 0, stream>>>(bsum, bpre);
    scan_final<<<NCHUNK, 256, 0, stream>>>(count, bpre, row_off, cursor);

    scatter_kernel<<<HIST_B, 256, 0, stream>>>(
        srcs[0], dsts[0], srcs[1], dsts[1], srcs[2], dsts[2], cursor, csr_idx);

    // ---- layer 0 ----
    {
        dim3 g(GX, 8, 3);
        gemm_proj3<<<g, 256, 0, stream>>>(xb, WtRel, projAll, N_NODES);
    }
    agg_fused<<<(N_NODES + 3) / 4, 256, 0, stream>>>(row_off, csr_idx, projAll, hm);
    gemm_fc<<<GX, 256, 0, stream>>>(hm, WtFc, bfc, ybuf, N_NODES);
    bn_reduce_kernel<<<256, 256, 0, stream>>>(ybuf, bnacc, bnacc + 64);

    // ---- layer 1 (bn of layer-0 fused into proj B-load) ----
    {
        dim3 g(GX, 8, 3);
        proj3_bn<<<g, 256, 0, stream>>>(ybuf, bnacc, bnacc + 64, gamma, beta,
                                        WtRel + (size_t)3 * 512 * 64, projAll, N_NODES);
    }
    agg_fused<<<(N_NODES + 3) / 4, 256, 0, stream>>>(row_off, csr_idx, projAll, hm);
    gemm_fc<<<GX, 256, 0, stream>>>(hm, WtFc + 64 * 64, bfc + HID, ybuf, N_NODES);
    bn_reduce_kernel<<<256, 256, 0, stream>>>(ybuf, bnacc + 128, bnacc + 192);

    // ---- final projection (bn of layer-1 fused) ----
    {
        dim3 g(GX, IN_DIM_ / 64);
        final_bn<<<g, 256, 0, stream>>>(ybuf, bnacc + 128, bnacc + 192,
                                        gamma + HID, beta + HID, WtDim, bdim, out, N_NODES);
    }
}